// Round 2
// baseline (54.626 us; speedup 1.0000x reference)
//
#include <hip/hip_runtime.h>
#include <hip/hip_bf16.h>

typedef float  f32x4  __attribute__((ext_vector_type(4)));
typedef float  f32x16 __attribute__((ext_vector_type(16)));
typedef int    i32x4  __attribute__((ext_vector_type(4)));
typedef __bf16 bf16x8 __attribute__((ext_vector_type(8)));

#define LL 256   // h*w
#define NF 32    // hidden dim
#define NCH 64   // channels

// pack two f32 -> one u32 of 2 bf16 (RNE; compiler emits v_cvt_pk_bf16_f32)
__device__ __forceinline__ unsigned pack2(float lo, float hi) {
    unsigned short a = __builtin_bit_cast(unsigned short, (__bf16)lo);
    unsigned short b = __builtin_bit_cast(unsigned short, (__bf16)hi);
    return (unsigned)a | ((unsigned)b << 16);
}

__device__ __forceinline__ bf16x8 words_to_frag(unsigned w0, unsigned w1, unsigned w2, unsigned w3) {
    i32x4 w;
    w.x = (int)w0; w.y = (int)w1; w.z = (int)w2; w.w = (int)w3;
    return __builtin_bit_cast(bf16x8, w);
}

// ---------------- phase 0: A'[b,l,k] = o @ W0[:64] + b0 ; B[b,l,k] = o @ W0[64:] ----------------
__global__ __launch_bounds__(256) void rn_pre(
    const float* __restrict__ x, const float* __restrict__ W0,
    const float* __restrict__ b0, float* __restrict__ Ap, float* __restrict__ Bp)
{
    int gid = blockIdx.x * 256 + threadIdx.x;   // 32*256*32 = 262144 threads
    int k  = gid & 31;
    int bl = gid >> 5;          // b*256 + l
    int b  = bl >> 8;
    int l  = bl & 255;
    const float* xrow = x + b * NCH * LL + l;   // x[b][ch][l]
    float accA = 0.f, accB = 0.f;
    #pragma unroll 8
    for (int ch = 0; ch < NCH; ++ch) {
        float xv = xrow[ch * LL];
        accA += xv * W0[ch * NF + k];
        accB += xv * W0[(NCH + ch) * NF + k];
    }
    Ap[gid] = accA + b0[k];
    Bp[gid] = accB;
}

// ---------------- phase 1: fused pair loop ----------------
// grid: 32 batches x 32 pblocks = 1024 blocks, 256 threads (4 waves)
// wave handles 2 p values x 8 q-tiles of 32 -> 32 pairs per MFMA tile
__global__ __launch_bounds__(256) void rn_main(
    const float* __restrict__ Ap, const float* __restrict__ Bp,
    const float* __restrict__ W1, const float* __restrict__ b1,
    const float* __restrict__ W2, const float* __restrict__ b2,
    float* __restrict__ partials)
{
    const int tid  = threadIdx.x;
    const int lane = tid & 63;
    const int w    = tid >> 6;
    const int col  = lane & 31;     // MFMA column index (pair within tile / m-col of W^T)
    const int hi   = lane >> 5;     // half-wave
    const int batch  = blockIdx.x >> 5;
    const int pblock = blockIdx.x & 31;

    // ---- constant A-operand fragments: A = W^T, slot(kh,hi,e) <- W[k = kh*16+8*hi+e][col] ----
    bf16x8 a1[2], a2[2];
    #pragma unroll
    for (int kh = 0; kh < 2; ++kh) {
        unsigned w1w[4], w2w[4];
        #pragma unroll
        for (int j = 0; j < 4; ++j) {
            int k0 = kh * 16 + 8 * hi + 2 * j;
            w1w[j] = pack2(W1[k0 * NF + col], W1[(k0 + 1) * NF + col]);
            w2w[j] = pack2(W2[k0 * NF + col], W2[(k0 + 1) * NF + col]);
        }
        a1[kh] = words_to_frag(w1w[0], w1w[1], w1w[2], w1w[3]);
        a2[kh] = words_to_frag(w2w[0], w2w[1], w2w[2], w2w[3]);
    }

    // ---- biases pre-arranged in the C/D register layout: row = (r&3)+8*(r>>2)+4*hi ----
    f32x16 bias1, bias2, sacc;
    #pragma unroll
    for (int r = 0; r < 16; ++r) {
        int row = (r & 3) + 8 * (r >> 2) + 4 * hi;
        bias1[r] = b1[row];
        bias2[r] = b2[row];
        sacc[r]  = 0.f;
    }

    const float* Abase = Ap + batch * LL * NF;
    const float* Bbase = Bp + batch * LL * NF;

    #pragma unroll 1
    for (int pi = 0; pi < 2; ++pi) {
        const int p = pblock * 8 + w * 2 + pi;
        const float* Brow = Bbase + p * NF;
        float bv[16];
        #pragma unroll
        for (int kh = 0; kh < 2; ++kh) {
            f32x4 t0 = *(const f32x4*)(Brow + kh * 16 + 8 * hi);
            f32x4 t1 = *(const f32x4*)(Brow + kh * 16 + 8 * hi + 4);
            bv[kh*8+0] = t0.x; bv[kh*8+1] = t0.y; bv[kh*8+2] = t0.z; bv[kh*8+3] = t0.w;
            bv[kh*8+4] = t1.x; bv[kh*8+5] = t1.y; bv[kh*8+6] = t1.z; bv[kh*8+7] = t1.w;
        }

        #pragma unroll 2
        for (int q0 = 0; q0 < LL; q0 += 32) {
            const float* Arow = Abase + (q0 + col) * NF;

            // build h1^T B-operand fragments: slot(kh,hi,e) <- h1[pair=q0+col][k=kh*16+8*hi+e]
            bf16x8 hf[2];
            #pragma unroll
            for (int kh = 0; kh < 2; ++kh) {
                f32x4 t0 = *(const f32x4*)(Arow + kh * 16 + 8 * hi);
                f32x4 t1 = *(const f32x4*)(Arow + kh * 16 + 8 * hi + 4);
                float h0 = fmaxf(t0.x + bv[kh*8+0], 0.f);
                float h1v = fmaxf(t0.y + bv[kh*8+1], 0.f);
                float h2v = fmaxf(t0.z + bv[kh*8+2], 0.f);
                float h3v = fmaxf(t0.w + bv[kh*8+3], 0.f);
                float h4v = fmaxf(t1.x + bv[kh*8+4], 0.f);
                float h5v = fmaxf(t1.y + bv[kh*8+5], 0.f);
                float h6v = fmaxf(t1.z + bv[kh*8+6], 0.f);
                float h7v = fmaxf(t1.w + bv[kh*8+7], 0.f);
                hf[kh] = words_to_frag(pack2(h0, h1v), pack2(h2v, h3v),
                                       pack2(h4v, h5v), pack2(h6v, h7v));
            }

            // layer 1: h2pre^T = W1^T . h1^T + b1  (bias via C-init)
            f32x16 acc1 = bias1;
            acc1 = __builtin_amdgcn_mfma_f32_32x32x16_bf16(a1[0], hf[0], acc1, 0, 0, 0);
            acc1 = __builtin_amdgcn_mfma_f32_32x32x16_bf16(a1[1], hf[1], acc1, 0, 0, 0);

            // epilogue 1: relu, pack rows pairwise to bf16 words
            // pk_t (t=0..7) holds rows m = {base_t + 4*hi, base_t+1 + 4*hi}, base = (t&1)*2 + (t>>1)*8
            unsigned pk0 = pack2(fmaxf(acc1[0],  0.f), fmaxf(acc1[1],  0.f)); // m = 4hi+{0,1}
            unsigned pk1 = pack2(fmaxf(acc1[2],  0.f), fmaxf(acc1[3],  0.f)); // m = 4hi+{2,3}
            unsigned pk2 = pack2(fmaxf(acc1[4],  0.f), fmaxf(acc1[5],  0.f)); // m = 8+4hi+{0,1}
            unsigned pk3 = pack2(fmaxf(acc1[6],  0.f), fmaxf(acc1[7],  0.f)); // m = 8+4hi+{2,3}
            unsigned pk4 = pack2(fmaxf(acc1[8],  0.f), fmaxf(acc1[9],  0.f)); // m = 16+4hi+{0,1}
            unsigned pk5 = pack2(fmaxf(acc1[10], 0.f), fmaxf(acc1[11], 0.f)); // m = 16+4hi+{2,3}
            unsigned pk6 = pack2(fmaxf(acc1[12], 0.f), fmaxf(acc1[13], 0.f)); // m = 24+4hi+{0,1}
            unsigned pk7 = pack2(fmaxf(acc1[14], 0.f), fmaxf(acc1[15], 0.f)); // m = 24+4hi+{2,3}

            // cross-half-wave exchange via unambiguous shfl_xor(32):
            // B2 slot word j of h2f0 must hold k = 8*hi + 2j,2j+1 (rows m=k of partner/self)
            unsigned q0w = __shfl_xor(pk0, 32, 64);
            unsigned q1w = __shfl_xor(pk1, 32, 64);
            unsigned q2w = __shfl_xor(pk2, 32, 64);
            unsigned q3w = __shfl_xor(pk3, 32, 64);
            unsigned q4w = __shfl_xor(pk4, 32, 64);
            unsigned q5w = __shfl_xor(pk5, 32, 64);
            unsigned q6w = __shfl_xor(pk6, 32, 64);
            unsigned q7w = __shfl_xor(pk7, 32, 64);
            // hi=0 lanes need k=0..7  : m 0..7   -> own pk0,pk1 then partner pk0,pk1
            // hi=1 lanes need k=8..15 : m 8..15  -> partner pk2,pk3 then own pk2,pk3
            unsigned w0 = hi ? q2w : pk0;
            unsigned w1 = hi ? q3w : pk1;
            unsigned w2 = hi ? pk2 : q0w;
            unsigned w3 = hi ? pk3 : q1w;
            // hi=0 lanes need k=16..23: m 16..23 -> own pk4,pk5 then partner pk4,pk5
            // hi=1 lanes need k=24..31: m 24..31 -> partner pk6,pk7 then own pk6,pk7
            unsigned w4 = hi ? q6w : pk4;
            unsigned w5 = hi ? q7w : pk5;
            unsigned w6 = hi ? pk6 : q4w;
            unsigned w7 = hi ? pk7 : q5w;
            bf16x8 h2f0 = words_to_frag(w0, w1, w2, w3);
            bf16x8 h2f1 = words_to_frag(w4, w5, w6, w7);

            // layer 2: h3pre^T = W2^T . h2^T + b2
            f32x16 acc2 = bias2;
            acc2 = __builtin_amdgcn_mfma_f32_32x32x16_bf16(a2[0], h2f0, acc2, 0, 0, 0);
            acc2 = __builtin_amdgcn_mfma_f32_32x32x16_bf16(a2[1], h2f1, acc2, 0, 0, 0);

            // accumulate relu(h3) into per-lane sums
            #pragma unroll
            for (int r = 0; r < 16; ++r) sacc[r] += fmaxf(acc2[r], 0.f);
        }
    }

    // ---- reduce: sum over pair-columns (lanes within each 32-half), then over waves ----
    float red[16];
    #pragma unroll
    for (int r = 0; r < 16; ++r) {
        float v = sacc[r];
        #pragma unroll
        for (int m = 1; m < 32; m <<= 1) v += __shfl_xor(v, m, 32);
        red[r] = v;
    }
    __shared__ float smem[4][32];
    if (col == 0) {
        #pragma unroll
        for (int r = 0; r < 16; ++r)
            smem[w][(r & 3) + 8 * (r >> 2) + 4 * hi] = red[r];
    }
    __syncthreads();
    if (tid < 32) {
        float s = smem[0][tid] + smem[1][tid] + smem[2][tid] + smem[3][tid];
        partials[blockIdx.x * 32 + tid] = s;
    }
}

// ---------------- phase 2: reduce partials + MLP head ----------------
__global__ __launch_bounds__(1024) void rn_post(
    const float* __restrict__ partials,
    const float* __restrict__ Wp, const float* __restrict__ bp,
    const float* __restrict__ Wo, const float* __restrict__ bo,
    float* __restrict__ out)
{
    __shared__ float s_lds[32][32];
    __shared__ float f_lds[32][32];
    int tid = threadIdx.x;
    int b = tid >> 5, n = tid & 31;
    float s = 0.f;
    #pragma unroll 4
    for (int pb = 0; pb < 32; ++pb) s += partials[(b * 32 + pb) * 32 + n];
    s_lds[b][n] = s;
    __syncthreads();
    float f = bp[n];
    #pragma unroll
    for (int k = 0; k < 32; ++k) f += s_lds[b][k] * Wp[k * 32 + n];
    f_lds[b][n] = fmaxf(f, 0.f);
    __syncthreads();
    float o = bo[n];
    #pragma unroll
    for (int k = 0; k < 32; ++k) o += f_lds[b][k] * Wo[k * 32 + n];
    out[tid] = o;
}

extern "C" void kernel_launch(void* const* d_in, const int* in_sizes, int n_in,
                              void* d_out, int out_size, void* d_ws, size_t ws_size,
                              hipStream_t stream)
{
    const float* x  = (const float*)d_in[0];
    const float* W0 = (const float*)d_in[1];
    const float* b0 = (const float*)d_in[2];
    const float* W1 = (const float*)d_in[3];
    const float* b1 = (const float*)d_in[4];
    const float* W2 = (const float*)d_in[5];
    const float* b2 = (const float*)d_in[6];
    const float* Wp = (const float*)d_in[7];
    const float* bp = (const float*)d_in[8];
    const float* Wo = (const float*)d_in[9];
    const float* bo = (const float*)d_in[10];
    float* out = (float*)d_out;

    float* Ap       = (float*)d_ws;            // 32*256*32 = 262144 f32
    float* Bp       = Ap + 32 * LL * NF;       // 262144 f32
    float* partials = Bp + 32 * LL * NF;       // 1024*32 = 32768 f32

    rn_pre <<<1024, 256, 0, stream>>>(x, W0, b0, Ap, Bp);
    rn_main<<<1024, 256, 0, stream>>>(Ap, Bp, W1, b1, W2, b2, partials);
    rn_post<<<1, 1024, 0, stream>>>(partials, Wp, bp, Wo, bo, out);
}